// Round 1
// baseline (118.855 us; speedup 1.0000x reference)
//
#include <hip/hip_runtime.h>
#include <math.h>

constexpr int Bdim = 32;
constexpr int Mdim = 8192;
constexpr int Idim = 256;
constexpr int CHUNKS = 64;                       // M-chunks for read_vector partials
constexpr int ROWS_PER_CHUNK = Mdim / CHUNKS;    // 128

// ---------------------------------------------------------------------------
// 1) projected_key[b,i] = tanh(sum_k key[b,k] * W[i,k] + bias[i])
//    grid = B, block = I (256). key row staged in LDS, W row per thread.
// ---------------------------------------------------------------------------
__global__ void proj_key_kernel(const float* __restrict__ key,
                                const float* __restrict__ W,
                                const float* __restrict__ bias,
                                float* __restrict__ pk) {
    int b = blockIdx.x;
    int i = threadIdx.x;
    __shared__ float kq[Idim];
    kq[i] = key[b * Idim + i];
    __syncthreads();
    const float4* w4 = (const float4*)(W + (size_t)i * Idim);
    const float4* k4 = (const float4*)kq;
    float s = bias[i];
    #pragma unroll 4
    for (int k = 0; k < Idim / 4; ++k) {
        float4 wv = w4[k];
        float4 kv = k4[k];
        s += wv.x * kv.x + wv.y * kv.y + wv.z * kv.z + wv.w * kv.w;
    }
    pk[b * Idim + i] = tanhf(s);
}

// ---------------------------------------------------------------------------
// 2) similarity[b,m] = -||pk[b,:] - memory[b,m,:]||^2
//    One wave per row: 64 lanes x float4 = 256 floats (1 KiB coalesced).
//    Block = 256 threads = 4 waves, each wave does 16 rows -> 64 rows/block.
// ---------------------------------------------------------------------------
__global__ void sim_kernel(const float* __restrict__ memory,
                           const float* __restrict__ pk,
                           float* __restrict__ sim) {
    constexpr int ROWS_PER_BLOCK = 64;
    constexpr int ROWS_PER_WAVE = 16;
    int blocks_per_b = Mdim / ROWS_PER_BLOCK;    // 128
    int b = blockIdx.x / blocks_per_b;
    int chunk = blockIdx.x % blocks_per_b;
    int wave = threadIdx.x >> 6;
    int lane = threadIdx.x & 63;

    float4 pkv = ((const float4*)(pk + b * Idim))[lane];

    int row0 = chunk * ROWS_PER_BLOCK + wave * ROWS_PER_WAVE;
    const float* base = memory + ((size_t)b * Mdim + row0) * Idim;
    size_t sim_base = (size_t)b * Mdim + row0;

    for (int r = 0; r < ROWS_PER_WAVE; ++r) {
        float4 mv = ((const float4*)(base + (size_t)r * Idim))[lane];
        float dx = pkv.x - mv.x, dy = pkv.y - mv.y;
        float dz = pkv.z - mv.z, dw = pkv.w - mv.w;
        float s = dx * dx + dy * dy + dz * dz + dw * dw;
        #pragma unroll
        for (int off = 32; off; off >>= 1) s += __shfl_xor(s, off, 64);
        if (lane == 0) sim[sim_base + r] = -s;
    }
}

// ---------------------------------------------------------------------------
// 3) weights[b,:] = softmax(beta[b] * sim[b,:])   (TEMPERATURE = 1)
//    One block (256 threads) per b. 8192 elements/row, 3 passes (L1/L2 hot).
// ---------------------------------------------------------------------------
__global__ void softmax_kernel(const float* __restrict__ sim,
                               const float* __restrict__ beta,
                               float* __restrict__ weights) {
    int b = blockIdx.x;
    float bt = beta[b];
    const float* s = sim + (size_t)b * Mdim;
    float* w = weights + (size_t)b * Mdim;
    int tid = threadIdx.x;
    int wave = tid >> 6, lane = tid & 63;
    __shared__ float redmax[4];
    __shared__ float redsum[4];

    // pass 1: max of bt * s
    float mx = -INFINITY;
    for (int m = tid; m < Mdim; m += 256) mx = fmaxf(mx, bt * s[m]);
    #pragma unroll
    for (int off = 32; off; off >>= 1) mx = fmaxf(mx, __shfl_xor(mx, off, 64));
    if (lane == 0) redmax[wave] = mx;
    __syncthreads();
    mx = fmaxf(fmaxf(redmax[0], redmax[1]), fmaxf(redmax[2], redmax[3]));

    // pass 2: exp + running sum (store unnormalized in weights)
    float sum = 0.f;
    for (int m = tid; m < Mdim; m += 256) {
        float e = __expf(bt * s[m] - mx);
        w[m] = e;
        sum += e;
    }
    #pragma unroll
    for (int off = 32; off; off >>= 1) sum += __shfl_xor(sum, off, 64);
    if (lane == 0) redsum[wave] = sum;
    __syncthreads();
    sum = redsum[0] + redsum[1] + redsum[2] + redsum[3];
    float inv = 1.f / sum;

    // pass 3: normalize
    for (int m = tid; m < Mdim; m += 256) w[m] *= inv;
}

// ---------------------------------------------------------------------------
// 4) partial[b,c,i] = sum_{m in chunk c} weights[b,m] * memory[b,m,i]
//    grid = B*CHUNKS, block = 256 (4 waves). Each wave covers rows r = wave,
//    wave+4, ... within the 128-row chunk; lane holds float4 of i-range.
// ---------------------------------------------------------------------------
__global__ void wsum_partial_kernel(const float* __restrict__ memory,
                                    const float* __restrict__ weights,
                                    float* __restrict__ partial) {
    int b = blockIdx.x / CHUNKS;
    int c = blockIdx.x % CHUNKS;
    int wave = threadIdx.x >> 6;
    int lane = threadIdx.x & 63;
    int m0 = c * ROWS_PER_CHUNK;
    const float* base = memory + ((size_t)b * Mdim + m0) * Idim;
    const float* wrow = weights + (size_t)b * Mdim + m0;

    float4 acc = make_float4(0.f, 0.f, 0.f, 0.f);
    for (int r = wave; r < ROWS_PER_CHUNK; r += 4) {
        float wv = wrow[r];
        float4 mv = ((const float4*)(base + (size_t)r * Idim))[lane];
        acc.x += wv * mv.x;
        acc.y += wv * mv.y;
        acc.z += wv * mv.z;
        acc.w += wv * mv.w;
    }

    __shared__ float lds[4][Idim];
    ((float4*)lds[wave])[lane] = acc;
    __syncthreads();
    int i = threadIdx.x;
    float v = lds[0][i] + lds[1][i] + lds[2][i] + lds[3][i];
    partial[((size_t)b * CHUNKS + c) * Idim + i] = v;
}

// ---------------------------------------------------------------------------
// 5) read_vector[b,i] = sum_c partial[b,c,i]
// ---------------------------------------------------------------------------
__global__ void wsum_reduce_kernel(const float* __restrict__ partial,
                                   float* __restrict__ out) {
    int b = blockIdx.x;
    int i = threadIdx.x;
    const float* p = partial + (size_t)b * CHUNKS * Idim + i;
    float s = 0.f;
    #pragma unroll 8
    for (int c = 0; c < CHUNKS; ++c) s += p[(size_t)c * Idim];
    out[(size_t)b * Idim + i] = s;
}

extern "C" void kernel_launch(void* const* d_in, const int* in_sizes, int n_in,
                              void* d_out, int out_size, void* d_ws, size_t ws_size,
                              hipStream_t stream) {
    const float* memory = (const float*)d_in[0];   // [B, M, I]
    const float* key    = (const float*)d_in[1];   // [B, I]
    const float* beta   = (const float*)d_in[2];   // [B]
    const float* W      = (const float*)d_in[3];   // [I, I]
    const float* bias   = (const float*)d_in[4];   // [I]

    float* out = (float*)d_out;
    float* weights  = out;                                     // [B, M]
    float* read_vec = out + (size_t)Bdim * Mdim;               // [B, I]
    float* sim      = read_vec + (size_t)Bdim * Idim;          // [B, M]

    float* pk      = (float*)d_ws;                             // [B, I]
    float* partial = pk + Bdim * Idim;                         // [B, CHUNKS, I]

    proj_key_kernel<<<Bdim, Idim, 0, stream>>>(key, W, bias, pk);
    sim_kernel<<<Bdim * (Mdim / 64), 256, 0, stream>>>(memory, pk, sim);
    softmax_kernel<<<Bdim, 256, 0, stream>>>(sim, beta, weights);
    wsum_partial_kernel<<<Bdim * CHUNKS, 256, 0, stream>>>(memory, weights, partial);
    wsum_reduce_kernel<<<Bdim, Idim, 0, stream>>>(partial, read_vec);
}

// Round 2
// 63.935 us; speedup vs baseline: 1.8590x; 1.8590x over previous
//
#include <hip/hip_runtime.h>
#include <math.h>

constexpr int Bdim = 32;
constexpr int Mdim = 8192;
constexpr int Idim = 256;
constexpr int ROWS_PER_BLOCK = 128;               // 4 waves x 32 rows
constexpr int ROWS_PER_WAVE = 32;
constexpr int NCHUNK = Mdim / ROWS_PER_BLOCK;     // 64 chunks per b

// ---------------------------------------------------------------------------
// 1) projected_key[b,i] = tanh(sum_k key[b,k] * W[i,k] + bias[i])
// ---------------------------------------------------------------------------
__global__ void proj_key_kernel(const float* __restrict__ key,
                                const float* __restrict__ W,
                                const float* __restrict__ bias,
                                float* __restrict__ pk) {
    int b = blockIdx.x;
    int i = threadIdx.x;
    __shared__ float kq[Idim];
    kq[i] = key[b * Idim + i];
    __syncthreads();
    const float4* w4 = (const float4*)(W + (size_t)i * Idim);
    const float4* k4 = (const float4*)kq;
    float s = bias[i];
    #pragma unroll 4
    for (int k = 0; k < Idim / 4; ++k) {
        float4 wv = w4[k];
        float4 kv = k4[k];
        s += wv.x * kv.x + wv.y * kv.y + wv.z * kv.z + wv.w * kv.w;
    }
    pk[b * Idim + i] = tanhf(s);
}

// ---------------------------------------------------------------------------
// 2) FUSED single pass over memory:
//    - sim[b,m] = -||pk - memory[b,m]||^2          (output)
//    - online-softmax chunk partials: mx_c, sum_c, vec_c[256]
//    One wave per row (64 lanes x float4 = 1 KiB coalesced); 32 rows/wave.
// ---------------------------------------------------------------------------
__global__ void fused_pass1_kernel(const float* __restrict__ memory,
                                   const float* __restrict__ pk,
                                   const float* __restrict__ beta,
                                   float* __restrict__ sim,
                                   float* __restrict__ pvec,
                                   float* __restrict__ pmx,
                                   float* __restrict__ psum) {
    int b = blockIdx.x / NCHUNK;
    int c = blockIdx.x % NCHUNK;
    int wave = threadIdx.x >> 6;
    int lane = threadIdx.x & 63;
    float bt = beta[b];

    float4 pkv = ((const float4*)(pk + b * Idim))[lane];

    int row0 = c * ROWS_PER_BLOCK + wave * ROWS_PER_WAVE;
    const float* base = memory + ((size_t)b * Mdim + row0) * Idim;
    float* simp = sim + (size_t)b * Mdim + row0;

    float mx = -INFINITY, ssum = 0.f;
    float4 acc = make_float4(0.f, 0.f, 0.f, 0.f);
    float my_sim = 0.f;                         // lane r keeps sim of row r

    for (int r = 0; r < ROWS_PER_WAVE; ++r) {
        float4 mv = ((const float4*)(base + (size_t)r * Idim))[lane];
        float dx = pkv.x - mv.x, dy = pkv.y - mv.y;
        float dz = pkv.z - mv.z, dw = pkv.w - mv.w;
        float s = dx * dx + dy * dy + dz * dz + dw * dw;
        #pragma unroll
        for (int off = 32; off; off >>= 1) s += __shfl_xor(s, off, 64);
        // all 64 lanes now hold the full distance s
        if (lane == r) my_sim = -s;

        float a = -bt * s;                      // beta * similarity
        float nmx = fmaxf(mx, a);
        float scale = __expf(mx - nmx);         // exp(-inf)=0 handles first row
        float p = __expf(a - nmx);
        ssum = ssum * scale + p;
        acc.x = acc.x * scale + p * mv.x;
        acc.y = acc.y * scale + p * mv.y;
        acc.z = acc.z * scale + p * mv.z;
        acc.w = acc.w * scale + p * mv.w;
        mx = nmx;
    }
    if (lane < ROWS_PER_WAVE) simp[lane] = my_sim;   // coalesced sim store

    // combine the block's 4 waves in LDS
    __shared__ float lacc[4][Idim];
    __shared__ float lmx[4], lsum[4];
    ((float4*)lacc[wave])[lane] = acc;
    if (lane == 0) { lmx[wave] = mx; lsum[wave] = ssum; }
    __syncthreads();

    float MX = fmaxf(fmaxf(lmx[0], lmx[1]), fmaxf(lmx[2], lmx[3]));
    float e0 = __expf(lmx[0] - MX), e1 = __expf(lmx[1] - MX);
    float e2 = __expf(lmx[2] - MX), e3 = __expf(lmx[3] - MX);
    int i = threadIdx.x;
    float v = lacc[0][i] * e0 + lacc[1][i] * e1 + lacc[2][i] * e2 + lacc[3][i] * e3;
    size_t pc = (size_t)b * NCHUNK + c;
    pvec[pc * Idim + i] = v;
    if (threadIdx.x == 0) {
        pmx[pc] = MX;
        psum[pc] = lsum[0] * e0 + lsum[1] * e1 + lsum[2] * e2 + lsum[3] * e3;
    }
}

// ---------------------------------------------------------------------------
// 3) per-b combine: global max/sum over 64 chunks, read_vector, save MX & 1/S
// ---------------------------------------------------------------------------
__global__ void combine_kernel(const float* __restrict__ pvec,
                               const float* __restrict__ pmx,
                               const float* __restrict__ psum,
                               float* __restrict__ read_vec,
                               float* __restrict__ MXb,
                               float* __restrict__ invb) {
    int b = blockIdx.x;
    int tid = threadIdx.x;
    __shared__ float e[NCHUNK];
    __shared__ float sInv;

    if (tid < NCHUNK) {                         // first wave handles scalars
        float m = pmx[(size_t)b * NCHUNK + tid];
        float mm = m;
        #pragma unroll
        for (int off = 32; off; off >>= 1) mm = fmaxf(mm, __shfl_xor(mm, off, 64));
        float ec = __expf(m - mm);
        e[tid] = ec;
        float sc = psum[(size_t)b * NCHUNK + tid] * ec;
        #pragma unroll
        for (int off = 32; off; off >>= 1) sc += __shfl_xor(sc, off, 64);
        if (tid == 0) {
            sInv = 1.f / sc;
            MXb[b] = mm;
            invb[b] = 1.f / sc;
        }
    }
    __syncthreads();

    float v = 0.f;
    const float* p = pvec + (size_t)b * NCHUNK * Idim + tid;
    #pragma unroll 8
    for (int c = 0; c < NCHUNK; ++c) v += p[(size_t)c * Idim] * e[c];
    read_vec[(size_t)b * Idim + tid] = v * sInv;
}

// ---------------------------------------------------------------------------
// 4) weights[b,m] = exp(beta[b]*sim[b,m] - MX[b]) * inv[b]
//    256 blocks x 256 threads x float4 = 256K elements
// ---------------------------------------------------------------------------
__global__ void weights_kernel(const float* __restrict__ sim,
                               const float* __restrict__ beta,
                               const float* __restrict__ MXb,
                               const float* __restrict__ invb,
                               float* __restrict__ weights) {
    int g = (blockIdx.x * 256 + threadIdx.x) * 4;
    int b = g >> 13;                            // / Mdim
    float bt = beta[b], MX = MXb[b], inv = invb[b];
    float4 s = *(const float4*)(sim + g);
    float4 w;
    w.x = __expf(bt * s.x - MX) * inv;
    w.y = __expf(bt * s.y - MX) * inv;
    w.z = __expf(bt * s.z - MX) * inv;
    w.w = __expf(bt * s.w - MX) * inv;
    *(float4*)(weights + g) = w;
}

extern "C" void kernel_launch(void* const* d_in, const int* in_sizes, int n_in,
                              void* d_out, int out_size, void* d_ws, size_t ws_size,
                              hipStream_t stream) {
    const float* memory = (const float*)d_in[0];   // [B, M, I]
    const float* key    = (const float*)d_in[1];   // [B, I]
    const float* beta   = (const float*)d_in[2];   // [B]
    const float* W      = (const float*)d_in[3];   // [I, I]
    const float* bias   = (const float*)d_in[4];   // [I]

    float* out = (float*)d_out;
    float* weights  = out;                                     // [B, M]
    float* read_vec = out + (size_t)Bdim * Mdim;               // [B, I]
    float* sim      = read_vec + (size_t)Bdim * Idim;          // [B, M]

    float* pk   = (float*)d_ws;                                // [B, I]
    float* pvec = pk + (size_t)Bdim * Idim;                    // [B, NCHUNK, I]
    float* pmx  = pvec + (size_t)Bdim * NCHUNK * Idim;         // [B, NCHUNK]
    float* psum = pmx + (size_t)Bdim * NCHUNK;                 // [B, NCHUNK]
    float* MXb  = psum + (size_t)Bdim * NCHUNK;                // [B]
    float* invb = MXb + Bdim;                                  // [B]

    proj_key_kernel<<<Bdim, Idim, 0, stream>>>(key, W, bias, pk);
    fused_pass1_kernel<<<Bdim * NCHUNK, 256, 0, stream>>>(memory, pk, beta,
                                                          sim, pvec, pmx, psum);
    combine_kernel<<<Bdim, Idim, 0, stream>>>(pvec, pmx, psum, read_vec, MXb, invb);
    weights_kernel<<<(Bdim * Mdim) / 1024, 256, 0, stream>>>(sim, beta, MXb, invb, weights);
}